// Round 1
// baseline (6798.048 us; speedup 1.0000x reference)
//
#include <hip/hip_runtime.h>
#include <stdint.h>
#include <stddef.h>

// ---------------------------------------------------------------------------
// Autoencoder: embed -> (2x enc LSTM + dec LSTM) -> attention -> mlp ->
// vocab logits -> masked mean NLL (scalar).
// All activations bf16 (stored as short), accumulation fp32.
// ---------------------------------------------------------------------------

typedef __attribute__((ext_vector_type(8))) short  sx8;
typedef __attribute__((ext_vector_type(8))) __bf16 bfx8;
typedef __attribute__((ext_vector_type(4))) float  fx4;

#define NCHUNK 251   // ceil(32003 / 128)

__device__ __forceinline__ float bf2f(short h) {
  unsigned u = ((unsigned)(unsigned short)h) << 16;
  return __builtin_bit_cast(float, u);
}
__device__ __forceinline__ short f2bf(float f) {
  unsigned u = __builtin_bit_cast(unsigned, f);
  u = (u + 0x7fffu + ((u >> 16) & 1u)) >> 16;
  return (short)u;
}
__device__ __forceinline__ fx4 mfma_bf16(sx8 a, sx8 b, fx4 c) {
  return __builtin_amdgcn_mfma_f32_16x16x32_bf16(
      __builtin_bit_cast(bfx8, a), __builtin_bit_cast(bfx8, b), c, 0, 0, 0);
}
__device__ __forceinline__ float sigm(float x) { return 1.f / (1.f + __expf(-x)); }
__device__ __forceinline__ float tanh_f(float x) { return 2.f / (1.f + __expf(-2.f * x)) - 1.f; }

// ---------------- fp32 -> bf16 convert ----------------
__global__ void k_f32_to_bf16(const float* __restrict__ src, short* __restrict__ dst, long n) {
  long i = (long)blockIdx.x * 256 + threadIdx.x;
  long stride = (long)gridDim.x * 256;
  for (; i < n; i += stride) dst[i] = f2bf(src[i]);
}

// ---------------- embedding gather (row 0..15 => token 0) ----------------
__global__ void k_embed(const float* __restrict__ emb, const int* __restrict__ idx,
                        short* __restrict__ dst, int rows) {
  long i = (long)blockIdx.x * 256 + threadIdx.x;
  if (i >= (long)rows * 512) return;
  int r = (int)(i >> 9), c = (int)(i & 511);
  int tok = (r < 16) ? 0 : idx[r - 16];
  dst[i] = f2bf(emb[(size_t)tok * 512 + c]);
}

// ---------------- generic BT GEMM: C[m][n] = sum_k A[m][k]*B[n][k] ----------
// 128x128 tile, BK=32, 4 waves (2x2), 16x16x32 MFMA. Strided + batched.
#define BM 128
#define BN 128
#define BK 32
__global__ __launch_bounds__(256) void k_gemm_bt(
    const short* __restrict__ A, long lda, long sA,
    const short* __restrict__ B, long ldb, long sB,
    short* __restrict__ Cb, float* __restrict__ Cf, long ldc, long sC,
    const float* __restrict__ bias, int relu,
    int M, int N, int K) {
  __shared__ short As[BM * BK];
  __shared__ short Bs[BN * BK];
  const int bz = blockIdx.z;
  const short* Ab = A + (size_t)bz * sA;
  const short* Bb = B + (size_t)bz * sB;
  const int m0 = blockIdx.x * BM, n0 = blockIdx.y * BN;
  const int tid = threadIdx.x;
  const int lane = tid & 63, wave = tid >> 6;
  const int wr = wave >> 1, wc = wave & 1;
  const int q = lane >> 4, l15 = lane & 15;
  const int sr = tid >> 2;          // staging row 0..63
  const int sc = (tid & 3) * 8;     // staging col offset (shorts)

  fx4 acc[4][4] = {};

  for (int k0 = 0; k0 < K; k0 += BK) {
    __syncthreads();
    *(sx8*)&As[ sr       * BK + sc] = *(const sx8*)(Ab + (size_t)(m0 + sr)      * lda + k0 + sc);
    *(sx8*)&As[(sr + 64) * BK + sc] = *(const sx8*)(Ab + (size_t)(m0 + sr + 64) * lda + k0 + sc);
    *(sx8*)&Bs[ sr       * BK + sc] = *(const sx8*)(Bb + (size_t)(n0 + sr)      * ldb + k0 + sc);
    *(sx8*)&Bs[(sr + 64) * BK + sc] = *(const sx8*)(Bb + (size_t)(n0 + sr + 64) * ldb + k0 + sc);
    __syncthreads();
    sx8 af[4], bf[4];
#pragma unroll
    for (int i = 0; i < 4; i++) af[i] = *(const sx8*)&As[(wr * 64 + i * 16 + l15) * BK + q * 8];
#pragma unroll
    for (int j = 0; j < 4; j++) bf[j] = *(const sx8*)&Bs[(wc * 64 + j * 16 + l15) * BK + q * 8];
#pragma unroll
    for (int i = 0; i < 4; i++)
#pragma unroll
      for (int j = 0; j < 4; j++) acc[i][j] = mfma_bf16(af[i], bf[j], acc[i][j]);
  }

#pragma unroll
  for (int i = 0; i < 4; i++) {
    int row0 = m0 + wr * 64 + i * 16 + q * 4;
#pragma unroll
    for (int j = 0; j < 4; j++) {
      int col = n0 + wc * 64 + j * 16 + l15;
      if (col >= N) continue;
      float bv = bias ? bias[col] : 0.f;
#pragma unroll
      for (int r = 0; r < 4; r++) {
        int row = row0 + r;
        if (row >= M) continue;
        float v = acc[i][j][r] + bv;
        if (relu) v = fmaxf(v, 0.f);
        size_t o = (size_t)bz * sC + (size_t)row * ldc + col;
        if (Cb) Cb[o] = f2bf(v);
        else    Cf[o] = v;
      }
    }
  }
}

// ---------------- logits GEMM with fused chunked log-sum-exp ----------------
// A = hid (8192 x K), B = out_W_bf16 (padded rows x K), bias = out_b.
// Writes per (row, n-chunk): max and sum(exp(v-max)) partials.
__global__ __launch_bounds__(256) void k_gemm_lse(
    const short* __restrict__ A, const short* __restrict__ B,
    const float* __restrict__ bias,
    float* __restrict__ mp, float* __restrict__ sp,
    int N, int K) {
  __shared__ short As[BM * BK];
  __shared__ short Bs[BN * BK];
  __shared__ float redm[2][2][64];
  __shared__ float reds[2][2][64];
  const int m0 = blockIdx.x * BM, n0 = blockIdx.y * BN;
  const int tid = threadIdx.x;
  const int lane = tid & 63, wave = tid >> 6;
  const int wr = wave >> 1, wc = wave & 1;
  const int q = lane >> 4, l15 = lane & 15;
  const int sr = tid >> 2, sc = (tid & 3) * 8;

  fx4 acc[4][4] = {};
  for (int k0 = 0; k0 < K; k0 += BK) {
    __syncthreads();
    *(sx8*)&As[ sr       * BK + sc] = *(const sx8*)(A + (size_t)(m0 + sr)      * K + k0 + sc);
    *(sx8*)&As[(sr + 64) * BK + sc] = *(const sx8*)(A + (size_t)(m0 + sr + 64) * K + k0 + sc);
    *(sx8*)&Bs[ sr       * BK + sc] = *(const sx8*)(B + (size_t)(n0 + sr)      * K + k0 + sc);
    *(sx8*)&Bs[(sr + 64) * BK + sc] = *(const sx8*)(B + (size_t)(n0 + sr + 64) * K + k0 + sc);
    __syncthreads();
    sx8 af[4], bf[4];
#pragma unroll
    for (int i = 0; i < 4; i++) af[i] = *(const sx8*)&As[(wr * 64 + i * 16 + l15) * BK + q * 8];
#pragma unroll
    for (int j = 0; j < 4; j++) bf[j] = *(const sx8*)&Bs[(wc * 64 + j * 16 + l15) * BK + q * 8];
#pragma unroll
    for (int i = 0; i < 4; i++)
#pragma unroll
      for (int j = 0; j < 4; j++) acc[i][j] = mfma_bf16(af[i], bf[j], acc[i][j]);
  }

#pragma unroll
  for (int i = 0; i < 4; i++) {
#pragma unroll
    for (int r = 0; r < 4; r++) {
      float vj[4], mx = -1e30f;
#pragma unroll
      for (int j = 0; j < 4; j++) {
        int col = n0 + wc * 64 + j * 16 + l15;
        float v = (col < N) ? (acc[i][j][r] + bias[col]) : -1e30f;
        vj[j] = v;
        mx = fmaxf(mx, v);
      }
#pragma unroll
      for (int off = 1; off < 16; off <<= 1) mx = fmaxf(mx, __shfl_xor(mx, off, 64));
      float s = 0.f;
#pragma unroll
      for (int j = 0; j < 4; j++) s += __expf(vj[j] - mx);  // masked -> exp(-1e30-mx)=0
#pragma unroll
      for (int off = 1; off < 16; off <<= 1) s += __shfl_xor(s, off, 64);
      if (l15 == 0) {
        int rl = i * 16 + q * 4 + r;
        redm[wr][wc][rl] = mx;
        reds[wr][wc][rl] = s;
      }
    }
  }
  __syncthreads();
  if (tid < 128) {
    int wrr = tid >> 6, rl = tid & 63;
    float ma = redm[wrr][0][rl], mb = redm[wrr][1][rl];
    float M2 = fmaxf(ma, mb);
    float S2 = reds[wrr][0][rl] * __expf(ma - M2) + reds[wrr][1][rl] * __expf(mb - M2);
    int grow = m0 + wrr * 64 + rl;
    mp[(size_t)blockIdx.y * 8192 + grow] = M2;
    sp[(size_t)blockIdx.y * 8192 + grow] = S2;
  }
}

// ---------------- fused 3-LSTM recurrence (persistent, spin barriers) -------
// Blocks 0..31: decoder (H=512); 32..47: enc fwd (H=256); 48..63: enc bwd.
// Each single-wave block owns 16 hidden units x 4 gates of Whh in LDS.
__global__ __launch_bounds__(64) void k_lstm(
    const short* __restrict__ xW_d, const short* __restrict__ Wh_d,
    const short* __restrict__ xW_f, const short* __restrict__ Wh_f,
    const short* __restrict__ xW_b, const short* __restrict__ Wh_b,
    short* __restrict__ h_d, short* __restrict__ h_f, short* __restrict__ h_b,
    short* __restrict__ full, short* __restrict__ enc,
    unsigned* __restrict__ ctrs) {
  __shared__ short Wsl[64 * 512];  // 64KB max (decoder); encoders use 32KB
  const int blk = blockIdx.x;
  const int lane = threadIdx.x;
  int group, gblk, nblk, Hd, T;
  const short *xW, *Whh;
  short* hbuf;
  unsigned* ctr;
  if (blk < 32)      { group = 0; gblk = blk;      nblk = 32; Hd = 512; T = 512; xW = xW_d; Whh = Wh_d; hbuf = h_d; ctr = ctrs;      }
  else if (blk < 48) { group = 1; gblk = blk - 32; nblk = 16; Hd = 256; T = 513; xW = xW_f; Whh = Wh_f; hbuf = h_f; ctr = ctrs + 16; }
  else               { group = 2; gblk = blk - 48; nblk = 16; Hd = 256; T = 513; xW = xW_b; Whh = Wh_b; hbuf = h_b; ctr = ctrs + 32; }
  const int K = Hd, nk = K >> 5, N4 = 4 * Hd;
  const int j0 = gblk * 16;
  const int q = lane >> 4, jj = lane & 15;

  // Stage Whh slice: LDS row rl = gate*16 + j_local  <->  global row gate*Hd+j0+j_local.
  // 16B chunks XOR-swizzled by (rl&7) to break the 1KB-row-stride bank aliasing.
  {
    const int cpr = K >> 3;
    const int total = 64 * cpr;
    for (int c = lane; c < total; c += 64) {
      int rl = c / cpr, c16 = c % cpr;
      int g = rl >> 4, j = rl & 15;
      sx8 v = *(const sx8*)(Whh + (size_t)(g * Hd + j0 + j) * K + (size_t)c16 * 8);
      *(sx8*)&Wsl[rl * K + ((c16 ^ (rl & 7)) << 3)] = v;
    }
  }
  __syncthreads();

  float cst[4] = {0.f, 0.f, 0.f, 0.f};  // cell state: rows b=q*4+r, col j0+jj

  for (int t = 0; t < T; t++) {
    const int trow = (group == 2) ? (512 - t) : t;
    // prefetch xW gate inputs (independent of h -> issues before h loads)
    float xg[4][4];
#pragma unroll
    for (int g = 0; g < 4; g++)
#pragma unroll
      for (int r = 0; r < 4; r++)
        xg[g][r] = bf2f(xW[(size_t)(trow * 16 + q * 4 + r) * N4 + g * Hd + j0 + jj]);

    const short* hp = hbuf + (t & 1) * 16 * Hd;
    short* hn = hbuf + ((t + 1) & 1) * 16 * Hd;

    sx8 afr[16];  // A frags: A[m=b][k], m=lane&15
    for (int kk = 0; kk < nk; kk++)
      afr[kk] = *(const sx8*)(hp + (size_t)jj * Hd + kk * 32 + q * 8);

    fx4 acc[4] = {};
    for (int kk = 0; kk < nk; kk++) {
      const int chunk = kk * 4 + q;
#pragma unroll
      for (int g = 0; g < 4; g++) {
        const int rl = g * 16 + jj;
        sx8 bfr = *(const sx8*)&Wsl[rl * K + ((chunk ^ (rl & 7)) << 3)];
        acc[g] = mfma_bf16(afr[kk], bfr, acc[g]);
      }
    }

#pragma unroll
    for (int r = 0; r < 4; r++) {
      const int b = q * 4 + r;
      float gi = acc[0][r] + xg[0][r];
      float gf = acc[1][r] + xg[1][r];
      float gc = acc[2][r] + xg[2][r];
      float go = acc[3][r] + xg[3][r];
      float cn = sigm(gf) * cst[r] + sigm(gi) * tanh_f(gc);
      cst[r] = cn;
      float hv = sigm(go) * tanh_f(cn);
      short h16 = f2bf(hv);
      hn[b * Hd + j0 + jj] = h16;
      if (group == 0)      full[(size_t)(t    * 16 + b) * 1024 + (j0 + jj)]        = h16;
      else if (group == 1) enc [(size_t)(trow * 16 + b) * 512  + (j0 + jj)]        = h16;
      else                 enc [(size_t)(trow * 16 + b) * 512  + 256 + (j0 + jj)]  = h16;
    }

    // group barrier (cumulative counter; zeroed by host memset each call)
    __threadfence();
    if (lane == 0) {
      __hip_atomic_fetch_add(ctr, 1u, __ATOMIC_RELAXED, __HIP_MEMORY_SCOPE_AGENT);
      unsigned target = (unsigned)nblk * (unsigned)(t + 1);
      while (__hip_atomic_load(ctr, __ATOMIC_RELAXED, __HIP_MEMORY_SCOPE_AGENT) < target)
        __builtin_amdgcn_s_sleep(1);
    }
    __threadfence();
  }
}

// ---------------- softmax over s (axis=1) of scores[b][s][t], in place ------
__global__ void k_softmax(short* __restrict__ scores) {
  const int b = blockIdx.y;
  const int t = blockIdx.x * 256 + threadIdx.x;  // 512 t's
  short* base = scores + (size_t)b * 513 * 512 + t;
  float mx = -1e30f;
  for (int s = 0; s < 513; s++) mx = fmaxf(mx, bf2f(base[s * 512]));
  float sum = 0.f;
  for (int s = 0; s < 513; s++) sum += __expf(bf2f(base[s * 512]) - mx);
  float inv = 1.f / sum;
  for (int s = 0; s < 513; s++) base[s * 512] = f2bf(__expf(bf2f(base[s * 512]) - mx) * inv);
}

// ---------------- batched tiled transpose: out[b][c][r] = in[b][r][c] -------
__global__ void k_transpose(const short* __restrict__ in, long ldi, long sbi,
                            short* __restrict__ out, long ldo, long sbo,
                            int rows, int cols) {
  __shared__ short tile[32][33];
  const int bz = blockIdx.z;
  const int r0 = blockIdx.x * 32, c0 = blockIdx.y * 32;
  const int tx = threadIdx.x & 31, ty = threadIdx.x >> 5;  // ty 0..7
#pragma unroll
  for (int i = 0; i < 4; i++) {
    int r = r0 + ty + i * 8, c = c0 + tx;
    short v = 0;
    if (r < rows) v = in[(size_t)bz * sbi + (size_t)r * ldi + c];
    tile[ty + i * 8][tx] = v;
  }
  __syncthreads();
#pragma unroll
  for (int i = 0; i < 4; i++) {
    int oc = c0 + ty + i * 8, orr = r0 + tx;
    if (orr < rows) out[(size_t)bz * sbo + (size_t)oc * ldo + orr] = tile[tx][ty + i * 8];
  }
}

// ---------------- target logit: tl[r] = dot(hid[r], W[tgt[r]]) + ob[tgt] ----
__global__ __launch_bounds__(256) void k_tl(const short* __restrict__ hid,
                                            const short* __restrict__ W,
                                            const float* __restrict__ ob,
                                            const int* __restrict__ tgt,
                                            float* __restrict__ tl) {
  const int row = blockIdx.x * 4 + (threadIdx.x >> 6);
  const int lane = threadIdx.x & 63;
  const int tv = tgt[row];
  sx8 hv = *(const sx8*)(hid + (size_t)row * 512 + lane * 8);
  sx8 wv = *(const sx8*)(W + (size_t)tv * 512 + lane * 8);
  float s = 0.f;
#pragma unroll
  for (int e = 0; e < 8; e++) s += bf2f(hv[e]) * bf2f(wv[e]);
#pragma unroll
  for (int off = 32; off >= 1; off >>= 1) s += __shfl_down(s, off, 64);
  if (lane == 0) tl[row] = s + ob[tv];
}

// ---------------- merge chunk partials -> masked NLL sums -------------------
__global__ __launch_bounds__(256) void k_nll(const float* __restrict__ mp,
                                             const float* __restrict__ sp,
                                             const float* __restrict__ tl,
                                             const int* __restrict__ tgt,
                                             float* __restrict__ accum) {
  const int r = blockIdx.x * 256 + threadIdx.x;
  float M = -1e30f, Ssum = 0.f;
  for (int c = 0; c < NCHUNK; c++) {
    float m = mp[(size_t)c * 8192 + r];
    float s = sp[(size_t)c * 8192 + r];
    float nM = fmaxf(M, m);
    Ssum = Ssum * __expf(M - nM) + s * __expf(m - nM);
    M = nM;
  }
  float msk = (tgt[r] != 0) ? 1.f : 0.f;
  float nll = (M + logf(Ssum) - tl[r]) * msk;
#pragma unroll
  for (int off = 32; off >= 1; off >>= 1) {
    nll += __shfl_down(nll, off, 64);
    msk += __shfl_down(msk, off, 64);
  }
  if ((threadIdx.x & 63) == 0) {
    atomicAdd(&accum[0], nll);
    atomicAdd(&accum[1], msk);
  }
}

__global__ void k_final(const float* __restrict__ accum, float* __restrict__ out) {
  out[0] = accum[0] / accum[1];
}

// ---------------------------------------------------------------------------
extern "C" void kernel_launch(void* const* d_in, const int* in_sizes, int n_in,
                              void* d_out, int out_size, void* d_ws, size_t ws_size,
                              hipStream_t stream) {
  (void)in_sizes; (void)n_in; (void)out_size;
  const int*   numeric = (const int*)  d_in[0];
  const int*   noised  = (const int*)  d_in[1];
  const float* emb     = (const float*)d_in[2];
  const float* Wih_f   = (const float*)d_in[3];
  const float* Whh_f   = (const float*)d_in[4];
  const float* b_f     = (const float*)d_in[5];
  const float* Wih_b   = (const float*)d_in[6];
  const float* Whh_b   = (const float*)d_in[7];
  const float* b_b     = (const float*)d_in[8];
  const float* dWih    = (const float*)d_in[9];
  const float* dWhh    = (const float*)d_in[10];
  const float* d_bv    = (const float*)d_in[11];
  const float* attnW   = (const float*)d_in[12];
  const float* mlpW    = (const float*)d_in[13];
  const float* mlp_b   = (const float*)d_in[14];
  const float* outW    = (const float*)d_in[15];
  const float* out_b   = (const float*)d_in[16];
  float* out = (float*)d_out;

  char* w = (char*)d_ws;
  size_t off = 0;
  auto alloc = [&](size_t bytes) -> void* {
    void* p = w + off;
    off = (off + bytes + 255) & ~(size_t)255;
    return p;
  };
  // bf16 weights
  short* bWih_f = (short*)alloc((size_t)1024 * 512 * 2);
  short* bWih_b = (short*)alloc((size_t)1024 * 512 * 2);
  short* bWhh_f = (short*)alloc((size_t)1024 * 256 * 2);
  short* bWhh_b = (short*)alloc((size_t)1024 * 256 * 2);
  short* bWdec  = (short*)alloc((size_t)2048 * 512 * 2);
  short* bWhhd  = (short*)alloc((size_t)2048 * 512 * 2);
  short* battnW = (short*)alloc((size_t)512 * 512 * 2);
  short* bmlpW  = (short*)alloc((size_t)512 * 1024 * 2);
  short* boutW  = (short*)alloc((size_t)32768 * 512 * 2);  // zero-padded rows
  // activations (bf16)
  short* embedded  = (short*)alloc((size_t)8192 * 512 * 2);
  short* embnoised = (short*)alloc((size_t)8208 * 512 * 2);
  short* g_xwf     = (short*)alloc((size_t)8208 * 1024 * 2);
  short* g_xwb     = (short*)alloc((size_t)8208 * 1024 * 2);
  short* g_xwd     = (short*)alloc((size_t)8192 * 2048 * 2);
  short* enc       = (short*)alloc((size_t)8208 * 512 * 2);
  short* proj      = (short*)alloc((size_t)8208 * 512 * 2);
  short* scores    = (short*)alloc((size_t)16 * 513 * 512 * 2);
  short* attnT     = (short*)alloc((size_t)16 * 512 * 544 * 2);
  short* encT      = (short*)alloc((size_t)16 * 512 * 544 * 2);
  short* full      = (short*)alloc((size_t)8192 * 1024 * 2);
  short* hid       = (short*)alloc((size_t)8192 * 512 * 2);
  float* mpart     = (float*)alloc((size_t)NCHUNK * 8192 * 4);
  float* spart     = (float*)alloc((size_t)NCHUNK * 8192 * 4);
  float* tlv       = (float*)alloc((size_t)8192 * 4);
  size_t small_off = off;
  short* h_d  = (short*)alloc(2 * 16 * 512 * 2);
  short* h_f  = (short*)alloc(2 * 16 * 256 * 2);
  short* h_b  = (short*)alloc(2 * 16 * 256 * 2);
  unsigned* ctrs  = (unsigned*)alloc(256);
  float*    accum = (float*)alloc(256);
  size_t total = off;
  if (ws_size < total) return;  // would corrupt; fail loudly via absmax

  dim3 b256(256);

  // zero-init regions (ws is poisoned before every call)
  hipMemsetAsync(boutW, 0, (size_t)32768 * 512 * 2, stream);
  hipMemsetAsync(attnT, 0, (size_t)16 * 512 * 544 * 2, stream);
  hipMemsetAsync(encT, 0, (size_t)16 * 512 * 544 * 2, stream);
  hipMemsetAsync(w + small_off, 0, total - small_off, stream);

  // weight conversions
  k_f32_to_bf16<<<2048, b256, 0, stream>>>(Wih_f, bWih_f, 1024L * 512);
  k_f32_to_bf16<<<2048, b256, 0, stream>>>(Wih_b, bWih_b, 1024L * 512);
  k_f32_to_bf16<<<2048, b256, 0, stream>>>(Whh_f, bWhh_f, 1024L * 256);
  k_f32_to_bf16<<<2048, b256, 0, stream>>>(Whh_b, bWhh_b, 1024L * 256);
  k_f32_to_bf16<<<2048, b256, 0, stream>>>(dWih,  bWdec,  2048L * 512);
  k_f32_to_bf16<<<2048, b256, 0, stream>>>(dWhh,  bWhhd,  2048L * 512);
  k_f32_to_bf16<<<2048, b256, 0, stream>>>(attnW, battnW, 512L * 512);
  k_f32_to_bf16<<<2048, b256, 0, stream>>>(mlpW,  bmlpW,  512L * 1024);
  k_f32_to_bf16<<<8192, b256, 0, stream>>>(outW,  boutW,  32003L * 512);

  // embeddings
  k_embed<<<(8192 * 512 + 255) / 256, b256, 0, stream>>>(emb, numeric, embedded, 8192);
  k_embed<<<(8208 * 512 + 255) / 256, b256, 0, stream>>>(emb, noised, embnoised, 8208);

  // xW = x @ Wih^T + b  (stored bf16)
  k_gemm_bt<<<dim3(65, 8, 1), b256, 0, stream>>>(embnoised, 512, 0, bWih_f, 512, 0,
      g_xwf, nullptr, 1024, 0, b_f, 0, 8208, 1024, 512);
  k_gemm_bt<<<dim3(65, 8, 1), b256, 0, stream>>>(embnoised, 512, 0, bWih_b, 512, 0,
      g_xwb, nullptr, 1024, 0, b_b, 0, 8208, 1024, 512);
  k_gemm_bt<<<dim3(64, 16, 1), b256, 0, stream>>>(embedded, 512, 0, bWdec, 512, 0,
      g_xwd, nullptr, 2048, 0, d_bv, 0, 8192, 2048, 512);

  // recurrences (dec -> full[:, :512], enc f/b -> enc)
  k_lstm<<<64, 64, 0, stream>>>(g_xwd, bWhhd, g_xwf, bWhh_f, g_xwb, bWhh_b,
                                h_d, h_f, h_b, full, enc, ctrs);

  // proj = enc @ attn_W^T
  k_gemm_bt<<<dim3(65, 4, 1), b256, 0, stream>>>(enc, 512, 0, battnW, 512, 0,
      proj, nullptr, 512, 0, nullptr, 0, 8208, 512, 512);

  // scores[b][s][t] = sum_h proj[s,b,h] * dec[t,b,h]   (dec lives in full[:, :512])
  k_gemm_bt<<<dim3(5, 4, 16), b256, 0, stream>>>(proj, 8192, 512, full, 16384, 1024,
      scores, nullptr, 512, (long)513 * 512, nullptr, 0, 513, 512, 512);

  // softmax over s, in place
  k_softmax<<<dim3(2, 16), b256, 0, stream>>>(scores);

  // transposes into K-padded (544) layouts
  k_transpose<<<dim3(17, 16, 16), b256, 0, stream>>>(scores, 512, (long)513 * 512,
      attnT, 544, (long)512 * 544, 513, 512);
  k_transpose<<<dim3(17, 16, 16), b256, 0, stream>>>(enc, 8192, 512,
      encT, 544, (long)512 * 544, 513, 512);

  // ctx[t,b,h] = sum_s attn[b,s,t] enc[s,b,h]  -> full[:, 512:]
  k_gemm_bt<<<dim3(4, 4, 16), b256, 0, stream>>>(attnT, 544, (long)512 * 544,
      encT, 544, (long)512 * 544,
      full + 512, nullptr, 16384, 1024, nullptr, 0, 512, 512, 544);

  // hid = relu(full @ mlp_W^T + mlp_b)
  k_gemm_bt<<<dim3(64, 4, 1), b256, 0, stream>>>(full, 1024, 0, bmlpW, 1024, 0,
      hid, nullptr, 512, 0, mlp_b, 1, 8192, 512, 1024);

  // fused logits + chunked log-sum-exp partials
  k_gemm_lse<<<dim3(64, NCHUNK), b256, 0, stream>>>(hid, boutW, out_b, mpart, spart,
                                                    32003, 512);
  // target logits
  k_tl<<<2048, b256, 0, stream>>>(hid, boutW, out_b, numeric, tlv);
  // merge + masked mean
  k_nll<<<32, b256, 0, stream>>>(mpart, spart, tlv, numeric, accum);
  k_final<<<1, 1, 0, stream>>>(accum, out);
}

// Round 2
// 5504.227 us; speedup vs baseline: 1.2351x; 1.2351x over previous
//
#include <hip/hip_runtime.h>
#include <stdint.h>
#include <stddef.h>

// ---------------------------------------------------------------------------
// Autoencoder: embed -> (2x enc LSTM + dec LSTM) -> attention -> mlp ->
// vocab logits -> masked mean NLL (scalar).
// All activations bf16 (stored as short), accumulation fp32.
// ---------------------------------------------------------------------------

typedef __attribute__((ext_vector_type(8))) short  sx8;
typedef __attribute__((ext_vector_type(8))) __bf16 bfx8;
typedef __attribute__((ext_vector_type(4))) float  fx4;

#define NCHUNK 251   // ceil(32003 / 128)

__device__ __forceinline__ float bf2f(short h) {
  unsigned u = ((unsigned)(unsigned short)h) << 16;
  return __builtin_bit_cast(float, u);
}
__device__ __forceinline__ short f2bf(float f) {
  unsigned u = __builtin_bit_cast(unsigned, f);
  u = (u + 0x7fffu + ((u >> 16) & 1u)) >> 16;
  return (short)u;
}
__device__ __forceinline__ fx4 mfma_bf16(sx8 a, sx8 b, fx4 c) {
  return __builtin_amdgcn_mfma_f32_16x16x32_bf16(
      __builtin_bit_cast(bfx8, a), __builtin_bit_cast(bfx8, b), c, 0, 0, 0);
}
__device__ __forceinline__ float sigm(float x) { return 1.f / (1.f + __expf(-x)); }
__device__ __forceinline__ float tanh_f(float x) { return 2.f / (1.f + __expf(-2.f * x)) - 1.f; }

// ---------------- fp32 -> bf16 convert ----------------
__global__ void k_f32_to_bf16(const float* __restrict__ src, short* __restrict__ dst, long n) {
  long i = (long)blockIdx.x * 256 + threadIdx.x;
  long stride = (long)gridDim.x * 256;
  for (; i < n; i += stride) dst[i] = f2bf(src[i]);
}

// ---------------- embedding gather (row 0..15 => token 0) ----------------
__global__ void k_embed(const float* __restrict__ emb, const int* __restrict__ idx,
                        short* __restrict__ dst, int rows) {
  long i = (long)blockIdx.x * 256 + threadIdx.x;
  if (i >= (long)rows * 512) return;
  int r = (int)(i >> 9), c = (int)(i & 511);
  int tok = (r < 16) ? 0 : idx[r - 16];
  dst[i] = f2bf(emb[(size_t)tok * 512 + c]);
}

// ---------------- generic BT GEMM: C[m][n] = sum_k A[m][k]*B[n][k] ----------
#define BM 128
#define BN 128
#define BK 32
__global__ __launch_bounds__(256) void k_gemm_bt(
    const short* __restrict__ A, long lda, long sA,
    const short* __restrict__ B, long ldb, long sB,
    short* __restrict__ Cb, float* __restrict__ Cf, long ldc, long sC,
    const float* __restrict__ bias, int relu,
    int M, int N, int K) {
  __shared__ short As[BM * BK];
  __shared__ short Bs[BN * BK];
  const int bz = blockIdx.z;
  const short* Ab = A + (size_t)bz * sA;
  const short* Bb = B + (size_t)bz * sB;
  const int m0 = blockIdx.x * BM, n0 = blockIdx.y * BN;
  const int tid = threadIdx.x;
  const int lane = tid & 63, wave = tid >> 6;
  const int wr = wave >> 1, wc = wave & 1;
  const int q = lane >> 4, l15 = lane & 15;
  const int sr = tid >> 2;          // staging row 0..63
  const int sc = (tid & 3) * 8;     // staging col offset (shorts)

  fx4 acc[4][4] = {};

  for (int k0 = 0; k0 < K; k0 += BK) {
    __syncthreads();
    *(sx8*)&As[ sr       * BK + sc] = *(const sx8*)(Ab + (size_t)(m0 + sr)      * lda + k0 + sc);
    *(sx8*)&As[(sr + 64) * BK + sc] = *(const sx8*)(Ab + (size_t)(m0 + sr + 64) * lda + k0 + sc);
    *(sx8*)&Bs[ sr       * BK + sc] = *(const sx8*)(Bb + (size_t)(n0 + sr)      * ldb + k0 + sc);
    *(sx8*)&Bs[(sr + 64) * BK + sc] = *(const sx8*)(Bb + (size_t)(n0 + sr + 64) * ldb + k0 + sc);
    __syncthreads();
    sx8 af[4], bf[4];
#pragma unroll
    for (int i = 0; i < 4; i++) af[i] = *(const sx8*)&As[(wr * 64 + i * 16 + l15) * BK + q * 8];
#pragma unroll
    for (int j = 0; j < 4; j++) bf[j] = *(const sx8*)&Bs[(wc * 64 + j * 16 + l15) * BK + q * 8];
#pragma unroll
    for (int i = 0; i < 4; i++)
#pragma unroll
      for (int j = 0; j < 4; j++) acc[i][j] = mfma_bf16(af[i], bf[j], acc[i][j]);
  }

#pragma unroll
  for (int i = 0; i < 4; i++) {
    int row0 = m0 + wr * 64 + i * 16 + q * 4;
#pragma unroll
    for (int j = 0; j < 4; j++) {
      int col = n0 + wc * 64 + j * 16 + l15;
      if (col >= N) continue;
      float bv = bias ? bias[col] : 0.f;
#pragma unroll
      for (int r = 0; r < 4; r++) {
        int row = row0 + r;
        if (row >= M) continue;
        float v = acc[i][j][r] + bv;
        if (relu) v = fmaxf(v, 0.f);
        size_t o = (size_t)bz * sC + (size_t)row * ldc + col;
        if (Cb) Cb[o] = f2bf(v);
        else    Cf[o] = v;
      }
    }
  }
}

// ---------------- logits GEMM with fused chunked log-sum-exp ----------------
__global__ __launch_bounds__(256) void k_gemm_lse(
    const short* __restrict__ A, const short* __restrict__ B,
    const float* __restrict__ bias,
    float* __restrict__ mp, float* __restrict__ sp,
    int N, int K) {
  __shared__ short As[BM * BK];
  __shared__ short Bs[BN * BK];
  __shared__ float redm[2][2][64];
  __shared__ float reds[2][2][64];
  const int m0 = blockIdx.x * BM, n0 = blockIdx.y * BN;
  const int tid = threadIdx.x;
  const int lane = tid & 63, wave = tid >> 6;
  const int wr = wave >> 1, wc = wave & 1;
  const int q = lane >> 4, l15 = lane & 15;
  const int sr = tid >> 2, sc = (tid & 3) * 8;

  fx4 acc[4][4] = {};
  for (int k0 = 0; k0 < K; k0 += BK) {
    __syncthreads();
    *(sx8*)&As[ sr       * BK + sc] = *(const sx8*)(A + (size_t)(m0 + sr)      * K + k0 + sc);
    *(sx8*)&As[(sr + 64) * BK + sc] = *(const sx8*)(A + (size_t)(m0 + sr + 64) * K + k0 + sc);
    *(sx8*)&Bs[ sr       * BK + sc] = *(const sx8*)(B + (size_t)(n0 + sr)      * K + k0 + sc);
    *(sx8*)&Bs[(sr + 64) * BK + sc] = *(const sx8*)(B + (size_t)(n0 + sr + 64) * K + k0 + sc);
    __syncthreads();
    sx8 af[4], bf[4];
#pragma unroll
    for (int i = 0; i < 4; i++) af[i] = *(const sx8*)&As[(wr * 64 + i * 16 + l15) * BK + q * 8];
#pragma unroll
    for (int j = 0; j < 4; j++) bf[j] = *(const sx8*)&Bs[(wc * 64 + j * 16 + l15) * BK + q * 8];
#pragma unroll
    for (int i = 0; i < 4; i++)
#pragma unroll
      for (int j = 0; j < 4; j++) acc[i][j] = mfma_bf16(af[i], bf[j], acc[i][j]);
  }

#pragma unroll
  for (int i = 0; i < 4; i++) {
#pragma unroll
    for (int r = 0; r < 4; r++) {
      float vj[4], mx = -1e30f;
#pragma unroll
      for (int j = 0; j < 4; j++) {
        int col = n0 + wc * 64 + j * 16 + l15;
        float v = (col < N) ? (acc[i][j][r] + bias[col]) : -1e30f;
        vj[j] = v;
        mx = fmaxf(mx, v);
      }
#pragma unroll
      for (int off = 1; off < 16; off <<= 1) mx = fmaxf(mx, __shfl_xor(mx, off, 64));
      float s = 0.f;
#pragma unroll
      for (int j = 0; j < 4; j++) s += __expf(vj[j] - mx);
#pragma unroll
      for (int off = 1; off < 16; off <<= 1) s += __shfl_xor(s, off, 64);
      if (l15 == 0) {
        int rl = i * 16 + q * 4 + r;
        redm[wr][wc][rl] = mx;
        reds[wr][wc][rl] = s;
      }
    }
  }
  __syncthreads();
  if (tid < 128) {
    int wrr = tid >> 6, rl = tid & 63;
    float ma = redm[wrr][0][rl], mb = redm[wrr][1][rl];
    float M2 = fmaxf(ma, mb);
    float S2 = reds[wrr][0][rl] * __expf(ma - M2) + reds[wrr][1][rl] * __expf(mb - M2);
    int grow = m0 + wrr * 64 + rl;
    mp[(size_t)blockIdx.y * 8192 + grow] = M2;
    sp[(size_t)blockIdx.y * 8192 + grow] = S2;
  }
}

// ---------------- fused 3-LSTM recurrence, register-resident Whh ------------
// 12 blocks x 256 thr. Blocks 0..7: decoder (H=512, 8 blk x 4 waves = 32 waves);
// 8..9: enc fwd (H=256, 8 waves); 10..11: enc bwd (8 waves).
// Each WAVE owns NU*16 hidden units x 4 gates; Whh B-frags live in VGPRs
// (64 sx8 = 256 VGPRs). Barrier: per-wave flag slots 64B apart, polled with
// one wave-wide load + __all -> no cacheline contention, no shared counter.
template<int NU, int NK, int HD, int T, int GRP>
__device__ __forceinline__ void lstm_body(
    const short* __restrict__ xW, const short* __restrict__ Whh,
    short* __restrict__ outb, const int ostride, const int ocol0,
    const short* __restrict__ zbuf,
    unsigned* __restrict__ flags, const int fbase, const int nw, const int gb) {
  constexpr int NT = 4 * NU;            // tiles = gates x units-per-lane-group
  constexpr int N4 = 4 * HD;
  const int lane = threadIdx.x & 63, wv = threadIdx.x >> 6;
  const int q = lane >> 4, l15 = lane & 15;
  const int j0 = gb * (NU * 64) + wv * (NU * 16);
  const int slot = fbase + gb * 4 + wv;

  // resident B-frags: bfr[tt][kk], tile tt=(g*NU+u) -> weight row g*HD+j0+u*16+l15
  sx8 bfr[NT][NK];
#pragma unroll
  for (int tt = 0; tt < NT; tt++) {
    const int g = tt / NU, u = tt % NU;
    const size_t wrow = (size_t)(g * HD + j0 + u * 16 + l15);
#pragma unroll
    for (int kk = 0; kk < NK; kk++)
      bfr[tt][kk] = *(const sx8*)(Whh + wrow * HD + kk * 32 + q * 8);
  }

  float cst[NU][4] = {};
  float xg[NT][4];
  {
    const int tr0 = (GRP == 2) ? (T - 1) : 0;
#pragma unroll
    for (int tt = 0; tt < NT; tt++) {
      const int g = tt / NU, u = tt % NU;
      const int cx = g * HD + j0 + u * 16 + l15;
#pragma unroll
      for (int r = 0; r < 4; r++)
        xg[tt][r] = bf2f(xW[(size_t)(tr0 * 16 + q * 4 + r) * N4 + cx]);
    }
  }

  for (int t = 0; t < T; t++) {
    const int trow = (GRP == 2) ? (T - 1 - t) : t;

    if (t > 0) {
      const unsigned tgt = (unsigned)t;
      while (true) {
        unsigned v = tgt;
        if (lane < nw)
          v = __hip_atomic_load(&flags[(size_t)(fbase + lane) * 16],
                                __ATOMIC_RELAXED, __HIP_MEMORY_SCOPE_AGENT);
        if (__all((int)(v >= tgt))) break;
        __builtin_amdgcn_s_sleep(1);
      }
      __threadfence();
    }

    const short* hp;
    if (t == 0) hp = zbuf;
    else {
      const int prow = (GRP == 2) ? (trow + 1) : (trow - 1);
      hp = outb + (size_t)(prow * 16) * ostride + ocol0;
    }
    sx8 afr[NK];
#pragma unroll
    for (int kk = 0; kk < NK; kk++)
      afr[kk] = *(const sx8*)(hp + (size_t)l15 * ostride + kk * 32 + q * 8);

    fx4 acc[NT] = {};
#pragma unroll
    for (int kk = 0; kk < NK; kk++)
#pragma unroll
      for (int tt = 0; tt < NT; tt++)
        acc[tt] = mfma_bf16(afr[kk], bfr[tt][kk], acc[tt]);

#pragma unroll
    for (int u = 0; u < NU; u++) {
      const int col = ocol0 + j0 + u * 16 + l15;
#pragma unroll
      for (int r = 0; r < 4; r++) {
        float gi = acc[0 * NU + u][r] + xg[0 * NU + u][r];
        float gf = acc[1 * NU + u][r] + xg[1 * NU + u][r];
        float gc = acc[2 * NU + u][r] + xg[2 * NU + u][r];
        float go = acc[3 * NU + u][r] + xg[3 * NU + u][r];
        float cn = sigm(gf) * cst[u][r] + sigm(gi) * tanh_f(gc);
        cst[u][r] = cn;
        outb[(size_t)(trow * 16 + q * 4 + r) * ostride + col] = f2bf(sigm(go) * tanh_f(cn));
      }
    }

    __threadfence();
    if (lane == 0)
      __hip_atomic_store(&flags[(size_t)slot * 16], (unsigned)(t + 1),
                         __ATOMIC_RELAXED, __HIP_MEMORY_SCOPE_AGENT);

    if (t + 1 < T) {  // prefetch next step's gate inputs while others finish
      const int ntr = (GRP == 2) ? (T - 2 - t) : (t + 1);
#pragma unroll
      for (int tt = 0; tt < NT; tt++) {
        const int g = tt / NU, u = tt % NU;
        const int cx = g * HD + j0 + u * 16 + l15;
#pragma unroll
        for (int r = 0; r < 4; r++)
          xg[tt][r] = bf2f(xW[(size_t)(ntr * 16 + q * 4 + r) * N4 + cx]);
      }
    }
  }
}

__global__ __launch_bounds__(256, 1) void k_lstm(
    const short* __restrict__ xW_d, const short* __restrict__ Wh_d,
    const short* __restrict__ xW_f, const short* __restrict__ Wh_f,
    const short* __restrict__ xW_b, const short* __restrict__ Wh_b,
    short* __restrict__ full, short* __restrict__ enc,
    const short* __restrict__ zbuf, unsigned* __restrict__ flags) {
  const int blk = blockIdx.x;
  if (blk < 8)
    lstm_body<1, 16, 512, 512, 0>(xW_d, Wh_d, full, 1024, 0,   zbuf, flags, 0, 32, blk);
  else if (blk < 10)
    lstm_body<2, 8, 256, 513, 1>(xW_f, Wh_f, enc, 512, 0,   zbuf, flags, 32, 8, blk - 8);
  else
    lstm_body<2, 8, 256, 513, 2>(xW_b, Wh_b, enc, 512, 256, zbuf, flags, 40, 8, blk - 10);
}

// ---------------- softmax over s (axis=1) of scores[b][s][t], in place ------
__global__ void k_softmax(short* __restrict__ scores) {
  const int b = blockIdx.y;
  const int t = blockIdx.x * 256 + threadIdx.x;
  short* base = scores + (size_t)b * 513 * 512 + t;
  float mx = -1e30f;
  for (int s = 0; s < 513; s++) mx = fmaxf(mx, bf2f(base[s * 512]));
  float sum = 0.f;
  for (int s = 0; s < 513; s++) sum += __expf(bf2f(base[s * 512]) - mx);
  float inv = 1.f / sum;
  for (int s = 0; s < 513; s++) base[s * 512] = f2bf(__expf(bf2f(base[s * 512]) - mx) * inv);
}

// ---------------- batched tiled transpose: out[b][c][r] = in[b][r][c] -------
__global__ void k_transpose(const short* __restrict__ in, long ldi, long sbi,
                            short* __restrict__ out, long ldo, long sbo,
                            int rows, int cols) {
  __shared__ short tile[32][33];
  const int bz = blockIdx.z;
  const int r0 = blockIdx.x * 32, c0 = blockIdx.y * 32;
  const int tx = threadIdx.x & 31, ty = threadIdx.x >> 5;
#pragma unroll
  for (int i = 0; i < 4; i++) {
    int r = r0 + ty + i * 8, c = c0 + tx;
    short v = 0;
    if (r < rows) v = in[(size_t)bz * sbi + (size_t)r * ldi + c];
    tile[ty + i * 8][tx] = v;
  }
  __syncthreads();
#pragma unroll
  for (int i = 0; i < 4; i++) {
    int oc = c0 + ty + i * 8, orr = r0 + tx;
    if (orr < rows) out[(size_t)bz * sbo + (size_t)oc * ldo + orr] = tile[tx][ty + i * 8];
  }
}

// ---------------- target logit: tl[r] = dot(hid[r], W[tgt[r]]) + ob[tgt] ----
__global__ __launch_bounds__(256) void k_tl(const short* __restrict__ hid,
                                            const short* __restrict__ W,
                                            const float* __restrict__ ob,
                                            const int* __restrict__ tgt,
                                            float* __restrict__ tl) {
  const int row = blockIdx.x * 4 + (threadIdx.x >> 6);
  const int lane = threadIdx.x & 63;
  const int tv = tgt[row];
  sx8 hv = *(const sx8*)(hid + (size_t)row * 512 + lane * 8);
  sx8 wv = *(const sx8*)(W + (size_t)tv * 512 + lane * 8);
  float s = 0.f;
#pragma unroll
  for (int e = 0; e < 8; e++) s += bf2f(hv[e]) * bf2f(wv[e]);
#pragma unroll
  for (int off = 32; off >= 1; off >>= 1) s += __shfl_down(s, off, 64);
  if (lane == 0) tl[row] = s + ob[tv];
}

// ---------------- merge chunk partials -> masked NLL sums -------------------
__global__ __launch_bounds__(256) void k_nll(const float* __restrict__ mp,
                                             const float* __restrict__ sp,
                                             const float* __restrict__ tl,
                                             const int* __restrict__ tgt,
                                             float* __restrict__ accum) {
  const int r = blockIdx.x * 256 + threadIdx.x;
  float M = -1e30f, Ssum = 0.f;
  for (int c = 0; c < NCHUNK; c++) {
    float m = mp[(size_t)c * 8192 + r];
    float s = sp[(size_t)c * 8192 + r];
    float nM = fmaxf(M, m);
    Ssum = Ssum * __expf(M - nM) + s * __expf(m - nM);
    M = nM;
  }
  float msk = (tgt[r] != 0) ? 1.f : 0.f;
  float nll = (M + logf(Ssum) - tl[r]) * msk;
#pragma unroll
  for (int off = 32; off >= 1; off >>= 1) {
    nll += __shfl_down(nll, off, 64);
    msk += __shfl_down(msk, off, 64);
  }
  if ((threadIdx.x & 63) == 0) {
    atomicAdd(&accum[0], nll);
    atomicAdd(&accum[1], msk);
  }
}

__global__ void k_final(const float* __restrict__ accum, float* __restrict__ out) {
  out[0] = accum[0] / accum[1];
}

// ---------------------------------------------------------------------------
extern "C" void kernel_launch(void* const* d_in, const int* in_sizes, int n_in,
                              void* d_out, int out_size, void* d_ws, size_t ws_size,
                              hipStream_t stream) {
  (void)in_sizes; (void)n_in; (void)out_size;
  const int*   numeric = (const int*)  d_in[0];
  const int*   noised  = (const int*)  d_in[1];
  const float* emb     = (const float*)d_in[2];
  const float* Wih_f   = (const float*)d_in[3];
  const float* Whh_f   = (const float*)d_in[4];
  const float* b_f     = (const float*)d_in[5];
  const float* Wih_b   = (const float*)d_in[6];
  const float* Whh_b   = (const float*)d_in[7];
  const float* b_b     = (const float*)d_in[8];
  const float* dWih    = (const float*)d_in[9];
  const float* dWhh    = (const float*)d_in[10];
  const float* d_bv    = (const float*)d_in[11];
  const float* attnW   = (const float*)d_in[12];
  const float* mlpW    = (const float*)d_in[13];
  const float* mlp_b   = (const float*)d_in[14];
  const float* outW    = (const float*)d_in[15];
  const float* out_b   = (const float*)d_in[16];
  float* out = (float*)d_out;

  char* w = (char*)d_ws;
  size_t off = 0;
  auto alloc = [&](size_t bytes) -> void* {
    void* p = w + off;
    off = (off + bytes + 255) & ~(size_t)255;
    return p;
  };
  // bf16 weights
  short* bWih_f = (short*)alloc((size_t)1024 * 512 * 2);
  short* bWih_b = (short*)alloc((size_t)1024 * 512 * 2);
  short* bWhh_f = (short*)alloc((size_t)1024 * 256 * 2);
  short* bWhh_b = (short*)alloc((size_t)1024 * 256 * 2);
  short* bWdec  = (short*)alloc((size_t)2048 * 512 * 2);
  short* bWhhd  = (short*)alloc((size_t)2048 * 512 * 2);
  short* battnW = (short*)alloc((size_t)512 * 512 * 2);
  short* bmlpW  = (short*)alloc((size_t)512 * 1024 * 2);
  short* boutW  = (short*)alloc((size_t)32768 * 512 * 2);  // zero-padded rows
  // activations (bf16)
  short* embedded  = (short*)alloc((size_t)8192 * 512 * 2);
  short* embnoised = (short*)alloc((size_t)8208 * 512 * 2);
  short* g_xwf     = (short*)alloc((size_t)8208 * 1024 * 2);
  short* g_xwb     = (short*)alloc((size_t)8208 * 1024 * 2);
  short* g_xwd     = (short*)alloc((size_t)8192 * 2048 * 2);
  short* enc       = (short*)alloc((size_t)8208 * 512 * 2);
  short* proj      = (short*)alloc((size_t)8208 * 512 * 2);
  short* scores    = (short*)alloc((size_t)16 * 513 * 512 * 2);
  short* attnT     = (short*)alloc((size_t)16 * 512 * 544 * 2);
  short* encT      = (short*)alloc((size_t)16 * 512 * 544 * 2);
  short* full      = (short*)alloc((size_t)8192 * 1024 * 2);
  short* hid       = (short*)alloc((size_t)8192 * 512 * 2);
  float* mpart     = (float*)alloc((size_t)NCHUNK * 8192 * 4);
  float* spart     = (float*)alloc((size_t)NCHUNK * 8192 * 4);
  float* tlv       = (float*)alloc((size_t)8192 * 4);
  size_t small_off = off;
  short*    zbuf  = (short*)alloc((size_t)16384 * 2);   // 32KB zeros (h0)
  unsigned* flags = (unsigned*)alloc(4096);             // 48 wave slots, 64B apart
  float*    accum = (float*)alloc(256);
  size_t total = off;
  if (ws_size < total) return;

  dim3 b256(256);

  // zero-init regions (ws is poisoned before every call)
  hipMemsetAsync(boutW, 0, (size_t)32768 * 512 * 2, stream);
  hipMemsetAsync(attnT, 0, (size_t)16 * 512 * 544 * 2, stream);
  hipMemsetAsync(encT, 0, (size_t)16 * 512 * 544 * 2, stream);
  hipMemsetAsync(w + small_off, 0, total - small_off, stream);

  // weight conversions
  k_f32_to_bf16<<<2048, b256, 0, stream>>>(Wih_f, bWih_f, 1024L * 512);
  k_f32_to_bf16<<<2048, b256, 0, stream>>>(Wih_b, bWih_b, 1024L * 512);
  k_f32_to_bf16<<<2048, b256, 0, stream>>>(Whh_f, bWhh_f, 1024L * 256);
  k_f32_to_bf16<<<2048, b256, 0, stream>>>(Whh_b, bWhh_b, 1024L * 256);
  k_f32_to_bf16<<<2048, b256, 0, stream>>>(dWih,  bWdec,  2048L * 512);
  k_f32_to_bf16<<<2048, b256, 0, stream>>>(dWhh,  bWhhd,  2048L * 512);
  k_f32_to_bf16<<<2048, b256, 0, stream>>>(attnW, battnW, 512L * 512);
  k_f32_to_bf16<<<2048, b256, 0, stream>>>(mlpW,  bmlpW,  512L * 1024);
  k_f32_to_bf16<<<8192, b256, 0, stream>>>(outW,  boutW,  32003L * 512);

  // embeddings
  k_embed<<<(8192 * 512 + 255) / 256, b256, 0, stream>>>(emb, numeric, embedded, 8192);
  k_embed<<<(8208 * 512 + 255) / 256, b256, 0, stream>>>(emb, noised, embnoised, 8208);

  // xW = x @ Wih^T + b  (stored bf16)
  k_gemm_bt<<<dim3(65, 8, 1), b256, 0, stream>>>(embnoised, 512, 0, bWih_f, 512, 0,
      g_xwf, nullptr, 1024, 0, b_f, 0, 8208, 1024, 512);
  k_gemm_bt<<<dim3(65, 8, 1), b256, 0, stream>>>(embnoised, 512, 0, bWih_b, 512, 0,
      g_xwb, nullptr, 1024, 0, b_b, 0, 8208, 1024, 512);
  k_gemm_bt<<<dim3(64, 16, 1), b256, 0, stream>>>(embedded, 512, 0, bWdec, 512, 0,
      g_xwd, nullptr, 2048, 0, d_bv, 0, 8192, 2048, 512);

  // recurrences (dec -> full[:, :512], enc f/b -> enc)
  k_lstm<<<12, b256, 0, stream>>>(g_xwd, bWhhd, g_xwf, bWhh_f, g_xwb, bWhh_b,
                                  full, enc, zbuf, flags);

  // proj = enc @ attn_W^T
  k_gemm_bt<<<dim3(65, 4, 1), b256, 0, stream>>>(enc, 512, 0, battnW, 512, 0,
      proj, nullptr, 512, 0, nullptr, 0, 8208, 512, 512);

  // scores[b][s][t] = sum_h proj[s,b,h] * dec[t,b,h]
  k_gemm_bt<<<dim3(5, 4, 16), b256, 0, stream>>>(proj, 8192, 512, full, 16384, 1024,
      scores, nullptr, 512, (long)513 * 512, nullptr, 0, 513, 512, 512);

  // softmax over s, in place
  k_softmax<<<dim3(2, 16), b256, 0, stream>>>(scores);

  // transposes into K-padded (544) layouts
  k_transpose<<<dim3(17, 16, 16), b256, 0, stream>>>(scores, 512, (long)513 * 512,
      attnT, 544, (long)512 * 544, 513, 512);
  k_transpose<<<dim3(17, 16, 16), b256, 0, stream>>>(enc, 8192, 512,
      encT, 544, (long)512 * 544, 513, 512);

  // ctx[t,b,h] = sum_s attn[b,s,t] enc[s,b,h]  -> full[:, 512:]
  k_gemm_bt<<<dim3(4, 4, 16), b256, 0, stream>>>(attnT, 544, (long)512 * 544,
      encT, 544, (long)512 * 544,
      full + 512, nullptr, 16384, 1024, nullptr, 0, 512, 512, 544);

  // hid = relu(full @ mlp_W^T + mlp_b)
  k_gemm_bt<<<dim3(64, 4, 1), b256, 0, stream>>>(full, 1024, 0, bmlpW, 1024, 0,
      hid, nullptr, 512, 0, mlp_b, 1, 8192, 512, 1024);

  // fused logits + chunked log-sum-exp partials
  k_gemm_lse<<<dim3(64, NCHUNK), b256, 0, stream>>>(hid, boutW, out_b, mpart, spart,
                                                    32003, 512);
  // target logits
  k_tl<<<2048, b256, 0, stream>>>(hid, boutW, out_b, numeric, tlv);
  // merge + masked mean
  k_nll<<<32, b256, 0, stream>>>(mpart, spart, tlv, numeric, accum);
  k_final<<<1, 1, 0, stream>>>(accum, out);
}

// Round 3
// 4427.883 us; speedup vs baseline: 1.5353x; 1.2431x over previous
//
#include <hip/hip_runtime.h>
#include <stdint.h>
#include <stddef.h>

// ---------------------------------------------------------------------------
// Autoencoder: embed -> (2x enc LSTM + dec LSTM) -> attention -> mlp ->
// vocab logits -> masked mean NLL (scalar).
// All activations bf16 (stored as short), accumulation fp32.
// LSTM cross-block communication: write-through (sc1) atomic stores to the
// coherence point + per-block flag lines. No __threadfence / buffer_wbl2.
// ---------------------------------------------------------------------------

typedef __attribute__((ext_vector_type(8))) short  sx8;
typedef __attribute__((ext_vector_type(8))) __bf16 bfx8;
typedef __attribute__((ext_vector_type(4))) float  fx4;

#define NCHUNK 251   // ceil(32003 / 128)

__device__ __forceinline__ float bf2f(short h) {
  unsigned u = ((unsigned)(unsigned short)h) << 16;
  return __builtin_bit_cast(float, u);
}
__device__ __forceinline__ short f2bf(float f) {
  unsigned u = __builtin_bit_cast(unsigned, f);
  u = (u + 0x7fffu + ((u >> 16) & 1u)) >> 16;
  return (short)u;
}
__device__ __forceinline__ fx4 mfma_bf16(sx8 a, sx8 b, fx4 c) {
  return __builtin_amdgcn_mfma_f32_16x16x32_bf16(
      __builtin_bit_cast(bfx8, a), __builtin_bit_cast(bfx8, b), c, 0, 0, 0);
}
__device__ __forceinline__ float sigm(float x) { return 1.f / (1.f + __expf(-x)); }
__device__ __forceinline__ float tanh_f(float x) { return 2.f / (1.f + __expf(-2.f * x)) - 1.f; }

// 8B coherence-point load (sc0 sc1): reads what write-through stores published.
__device__ __forceinline__ unsigned long long cp_load_u64(const void* p) {
  return __hip_atomic_load((const unsigned long long*)p,
                           __ATOMIC_RELAXED, __HIP_MEMORY_SCOPE_AGENT);
}
__device__ __forceinline__ sx8 cp_load_sx8(const void* p) {
  union { unsigned long long u[2]; sx8 v; } cvt;
  cvt.u[0] = cp_load_u64(p);
  cvt.u[1] = cp_load_u64((const char*)p + 8);
  return cvt.v;
}

// ---------------- fp32 -> bf16 convert ----------------
__global__ void k_f32_to_bf16(const float* __restrict__ src, short* __restrict__ dst, long n) {
  long i = (long)blockIdx.x * 256 + threadIdx.x;
  long stride = (long)gridDim.x * 256;
  for (; i < n; i += stride) dst[i] = f2bf(src[i]);
}

// ---------------- embedding gather (row 0..15 => token 0) ----------------
__global__ void k_embed(const float* __restrict__ emb, const int* __restrict__ idx,
                        short* __restrict__ dst, int rows) {
  long i = (long)blockIdx.x * 256 + threadIdx.x;
  if (i >= (long)rows * 512) return;
  int r = (int)(i >> 9), c = (int)(i & 511);
  int tok = (r < 16) ? 0 : idx[r - 16];
  dst[i] = f2bf(emb[(size_t)tok * 512 + c]);
}

// ---------------- generic BT GEMM: C[m][n] = sum_k A[m][k]*B[n][k] ----------
#define BM 128
#define BN 128
#define BK 32
__global__ __launch_bounds__(256) void k_gemm_bt(
    const short* __restrict__ A, long lda, long sA,
    const short* __restrict__ B, long ldb, long sB,
    short* __restrict__ Cb, float* __restrict__ Cf, long ldc, long sC,
    const float* __restrict__ bias, int relu,
    int M, int N, int K) {
  __shared__ short As[BM * BK];
  __shared__ short Bs[BN * BK];
  const int bz = blockIdx.z;
  const short* Ab = A + (size_t)bz * sA;
  const short* Bb = B + (size_t)bz * sB;
  const int m0 = blockIdx.x * BM, n0 = blockIdx.y * BN;
  const int tid = threadIdx.x;
  const int lane = tid & 63, wave = tid >> 6;
  const int wr = wave >> 1, wc = wave & 1;
  const int q = lane >> 4, l15 = lane & 15;
  const int sr = tid >> 2;          // staging row 0..63
  const int sc = (tid & 3) * 8;     // staging col offset (shorts)

  fx4 acc[4][4] = {};

  for (int k0 = 0; k0 < K; k0 += BK) {
    __syncthreads();
    *(sx8*)&As[ sr       * BK + sc] = *(const sx8*)(Ab + (size_t)(m0 + sr)      * lda + k0 + sc);
    *(sx8*)&As[(sr + 64) * BK + sc] = *(const sx8*)(Ab + (size_t)(m0 + sr + 64) * lda + k0 + sc);
    *(sx8*)&Bs[ sr       * BK + sc] = *(const sx8*)(Bb + (size_t)(n0 + sr)      * ldb + k0 + sc);
    *(sx8*)&Bs[(sr + 64) * BK + sc] = *(const sx8*)(Bb + (size_t)(n0 + sr + 64) * ldb + k0 + sc);
    __syncthreads();
    sx8 af[4], bf[4];
#pragma unroll
    for (int i = 0; i < 4; i++) af[i] = *(const sx8*)&As[(wr * 64 + i * 16 + l15) * BK + q * 8];
#pragma unroll
    for (int j = 0; j < 4; j++) bf[j] = *(const sx8*)&Bs[(wc * 64 + j * 16 + l15) * BK + q * 8];
#pragma unroll
    for (int i = 0; i < 4; i++)
#pragma unroll
      for (int j = 0; j < 4; j++) acc[i][j] = mfma_bf16(af[i], bf[j], acc[i][j]);
  }

#pragma unroll
  for (int i = 0; i < 4; i++) {
    int row0 = m0 + wr * 64 + i * 16 + q * 4;
#pragma unroll
    for (int j = 0; j < 4; j++) {
      int col = n0 + wc * 64 + j * 16 + l15;
      if (col >= N) continue;
      float bv = bias ? bias[col] : 0.f;
#pragma unroll
      for (int r = 0; r < 4; r++) {
        int row = row0 + r;
        if (row >= M) continue;
        float v = acc[i][j][r] + bv;
        if (relu) v = fmaxf(v, 0.f);
        size_t o = (size_t)bz * sC + (size_t)row * ldc + col;
        if (Cb) Cb[o] = f2bf(v);
        else    Cf[o] = v;
      }
    }
  }
}

// ---------------- logits GEMM with fused chunked log-sum-exp ----------------
__global__ __launch_bounds__(256) void k_gemm_lse(
    const short* __restrict__ A, const short* __restrict__ B,
    const float* __restrict__ bias,
    float* __restrict__ mp, float* __restrict__ sp,
    int N, int K) {
  __shared__ short As[BM * BK];
  __shared__ short Bs[BN * BK];
  __shared__ float redm[2][2][64];
  __shared__ float reds[2][2][64];
  const int m0 = blockIdx.x * BM, n0 = blockIdx.y * BN;
  const int tid = threadIdx.x;
  const int lane = tid & 63, wave = tid >> 6;
  const int wr = wave >> 1, wc = wave & 1;
  const int q = lane >> 4, l15 = lane & 15;
  const int sr = tid >> 2, sc = (tid & 3) * 8;

  fx4 acc[4][4] = {};
  for (int k0 = 0; k0 < K; k0 += BK) {
    __syncthreads();
    *(sx8*)&As[ sr       * BK + sc] = *(const sx8*)(A + (size_t)(m0 + sr)      * K + k0 + sc);
    *(sx8*)&As[(sr + 64) * BK + sc] = *(const sx8*)(A + (size_t)(m0 + sr + 64) * K + k0 + sc);
    *(sx8*)&Bs[ sr       * BK + sc] = *(const sx8*)(B + (size_t)(n0 + sr)      * K + k0 + sc);
    *(sx8*)&Bs[(sr + 64) * BK + sc] = *(const sx8*)(B + (size_t)(n0 + sr + 64) * K + k0 + sc);
    __syncthreads();
    sx8 af[4], bf[4];
#pragma unroll
    for (int i = 0; i < 4; i++) af[i] = *(const sx8*)&As[(wr * 64 + i * 16 + l15) * BK + q * 8];
#pragma unroll
    for (int j = 0; j < 4; j++) bf[j] = *(const sx8*)&Bs[(wc * 64 + j * 16 + l15) * BK + q * 8];
#pragma unroll
    for (int i = 0; i < 4; i++)
#pragma unroll
      for (int j = 0; j < 4; j++) acc[i][j] = mfma_bf16(af[i], bf[j], acc[i][j]);
  }

#pragma unroll
  for (int i = 0; i < 4; i++) {
#pragma unroll
    for (int r = 0; r < 4; r++) {
      float vj[4], mx = -1e30f;
#pragma unroll
      for (int j = 0; j < 4; j++) {
        int col = n0 + wc * 64 + j * 16 + l15;
        float v = (col < N) ? (acc[i][j][r] + bias[col]) : -1e30f;
        vj[j] = v;
        mx = fmaxf(mx, v);
      }
#pragma unroll
      for (int off = 1; off < 16; off <<= 1) mx = fmaxf(mx, __shfl_xor(mx, off, 64));
      float s = 0.f;
#pragma unroll
      for (int j = 0; j < 4; j++) s += __expf(vj[j] - mx);
#pragma unroll
      for (int off = 1; off < 16; off <<= 1) s += __shfl_xor(s, off, 64);
      if (l15 == 0) {
        int rl = i * 16 + q * 4 + r;
        redm[wr][wc][rl] = mx;
        reds[wr][wc][rl] = s;
      }
    }
  }
  __syncthreads();
  if (tid < 128) {
    int wrr = tid >> 6, rl = tid & 63;
    float ma = redm[wrr][0][rl], mb = redm[wrr][1][rl];
    float M2 = fmaxf(ma, mb);
    float S2 = reds[wrr][0][rl] * __expf(ma - M2) + reds[wrr][1][rl] * __expf(mb - M2);
    int grow = m0 + wrr * 64 + rl;
    mp[(size_t)blockIdx.y * 8192 + grow] = M2;
    sp[(size_t)blockIdx.y * 8192 + grow] = S2;
  }
}

// ---------------- fused 3-LSTM recurrence, register-resident Whh ------------
// 12 blocks x 256 thr. Blocks 0..7: decoder (H=512); 8..9: enc fwd; 10..11:
// enc bwd. Each wave owns NU*16 hidden units x 4 gates; Whh B-frags resident
// in VGPR/AGPR. h published via write-through (sc0 sc1) atomic dword stores;
// one flag per block, group's flags packed in one cacheline; consumers read
// h via 8B coherence-point atomic loads. No threadfence.
template<int NU, int NK, int HD, int T, int GRP>
__device__ __forceinline__ void lstm_body(
    const short* __restrict__ xW, const short* __restrict__ Whh,
    short* __restrict__ outb, const int ostride, const int ocol0,
    const short* __restrict__ zbuf,
    unsigned* __restrict__ flags, const int fbase, const int nb, const int gb) {
  constexpr int NT = 4 * NU;            // tiles = gates x units-per-wave/16
  constexpr int N4 = 4 * HD;
  const int lane = threadIdx.x & 63, wv = threadIdx.x >> 6;
  const int q = lane >> 4, l15 = lane & 15;
  const int j0 = gb * (NU * 64) + wv * (NU * 16);

  // resident B-frags: bfr[tt][kk], tile tt=(g*NU+u) -> weight row g*HD+j0+u*16+l15
  sx8 bfr[NT][NK];
#pragma unroll
  for (int tt = 0; tt < NT; tt++) {
    const int g = tt / NU, u = tt % NU;
    const size_t wrow = (size_t)(g * HD + j0 + u * 16 + l15);
#pragma unroll
    for (int kk = 0; kk < NK; kk++)
      bfr[tt][kk] = *(const sx8*)(Whh + wrow * HD + kk * 32 + q * 8);
  }

  float cst[NU][4] = {};
  float xg[NT][4];
  {
    const int tr0 = (GRP == 2) ? (T - 1) : 0;
#pragma unroll
    for (int tt = 0; tt < NT; tt++) {
      const int g = tt / NU, u = tt % NU;
      const int cx = g * HD + j0 + u * 16 + l15;
#pragma unroll
      for (int r = 0; r < 4; r++)
        xg[tt][r] = bf2f(xW[(size_t)(tr0 * 16 + q * 4 + r) * N4 + cx]);
    }
  }

  for (int t = 0; t < T; t++) {
    const int trow = (GRP == 2) ? (T - 1 - t) : t;

    if (t > 0) {  // wait for all blocks of this group to have published step t-1
      const unsigned tgt = (unsigned)t;
      while (true) {
        unsigned v = tgt;
        if (lane < nb)
          v = __hip_atomic_load(&flags[fbase + lane],
                                __ATOMIC_RELAXED, __HIP_MEMORY_SCOPE_AGENT);
        if (__all((int)(v >= tgt))) break;
      }
    }

    const short* hp;
    if (t == 0) hp = zbuf;
    else {
      const int prow = (GRP == 2) ? (trow + 1) : (trow - 1);
      hp = outb + (size_t)(prow * 16) * ostride + ocol0;
    }
    sx8 afr[NK];
#pragma unroll
    for (int kk = 0; kk < NK; kk++)
      afr[kk] = cp_load_sx8(hp + (size_t)l15 * ostride + kk * 32 + q * 8);

    fx4 acc[NT] = {};
#pragma unroll
    for (int kk = 0; kk < NK; kk++)
#pragma unroll
      for (int tt = 0; tt < NT; tt++)
        acc[tt] = mfma_bf16(afr[kk], bfr[tt][kk], acc[tt]);

#pragma unroll
    for (int u = 0; u < NU; u++) {
      const int colb = ocol0 + j0 + u * 16 + (l15 & ~1);
#pragma unroll
      for (int r = 0; r < 4; r++) {
        float gi = acc[0 * NU + u][r] + xg[0 * NU + u][r];
        float gf = acc[1 * NU + u][r] + xg[1 * NU + u][r];
        float gc = acc[2 * NU + u][r] + xg[2 * NU + u][r];
        float go = acc[3 * NU + u][r] + xg[3 * NU + u][r];
        float cn = sigm(gf) * cst[u][r] + sigm(gi) * tanh_f(gc);
        cst[u][r] = cn;
        unsigned mine = (unsigned)(unsigned short)f2bf(sigm(go) * tanh_f(cn));
        unsigned other = (unsigned)__shfl_xor((int)mine, 1, 64);
        if (!(l15 & 1)) {  // even lane stores packed pair write-through
          unsigned dw = mine | (other << 16);
          unsigned* dst = (unsigned*)(outb + (size_t)(trow * 16 + q * 4 + r) * ostride + colb);
          __hip_atomic_store(dst, dw, __ATOMIC_RELAXED, __HIP_MEMORY_SCOPE_AGENT);
        }
      }
    }

    __syncthreads();  // implicit vmcnt(0): all 4 waves' stores ack'd at IF$
    if (threadIdx.x == 0)
      __hip_atomic_store(&flags[fbase + gb], (unsigned)(t + 1),
                         __ATOMIC_RELAXED, __HIP_MEMORY_SCOPE_AGENT);

    if (t + 1 < T) {  // prefetch next step's gate inputs while others finish
      const int ntr = (GRP == 2) ? (T - 2 - t) : (t + 1);
#pragma unroll
      for (int tt = 0; tt < NT; tt++) {
        const int g = tt / NU, u = tt % NU;
        const int cx = g * HD + j0 + u * 16 + l15;
#pragma unroll
        for (int r = 0; r < 4; r++)
          xg[tt][r] = bf2f(xW[(size_t)(ntr * 16 + q * 4 + r) * N4 + cx]);
      }
    }
  }
}

__global__ __launch_bounds__(256, 1) void k_lstm(
    const short* __restrict__ xW_d, const short* __restrict__ Wh_d,
    const short* __restrict__ xW_f, const short* __restrict__ Wh_f,
    const short* __restrict__ xW_b, const short* __restrict__ Wh_b,
    short* __restrict__ full, short* __restrict__ enc,
    const short* __restrict__ zbuf, unsigned* __restrict__ flags) {
  const int blk = blockIdx.x;
  // flag lines (dword idx): dec 0..7 @0, enc_f 0..1 @32, enc_b 0..1 @64
  if (blk < 8)
    lstm_body<1, 16, 512, 512, 0>(xW_d, Wh_d, full, 1024, 0,   zbuf, flags, 0, 8, blk);
  else if (blk < 10)
    lstm_body<2, 8, 256, 513, 1>(xW_f, Wh_f, enc, 512, 0,   zbuf, flags, 32, 2, blk - 8);
  else
    lstm_body<2, 8, 256, 513, 2>(xW_b, Wh_b, enc, 512, 256, zbuf, flags, 64, 2, blk - 10);
}

// ---------------- softmax over s (axis=1) of scores[b][s][t], in place ------
__global__ void k_softmax(short* __restrict__ scores) {
  const int b = blockIdx.y;
  const int t = blockIdx.x * 256 + threadIdx.x;
  short* base = scores + (size_t)b * 513 * 512 + t;
  float mx = -1e30f;
  for (int s = 0; s < 513; s++) mx = fmaxf(mx, bf2f(base[s * 512]));
  float sum = 0.f;
  for (int s = 0; s < 513; s++) sum += __expf(bf2f(base[s * 512]) - mx);
  float inv = 1.f / sum;
  for (int s = 0; s < 513; s++) base[s * 512] = f2bf(__expf(bf2f(base[s * 512]) - mx) * inv);
}

// ---------------- batched tiled transpose: out[b][c][r] = in[b][r][c] -------
__global__ void k_transpose(const short* __restrict__ in, long ldi, long sbi,
                            short* __restrict__ out, long ldo, long sbo,
                            int rows, int cols) {
  __shared__ short tile[32][33];
  const int bz = blockIdx.z;
  const int r0 = blockIdx.x * 32, c0 = blockIdx.y * 32;
  const int tx = threadIdx.x & 31, ty = threadIdx.x >> 5;
#pragma unroll
  for (int i = 0; i < 4; i++) {
    int r = r0 + ty + i * 8, c = c0 + tx;
    short v = 0;
    if (r < rows) v = in[(size_t)bz * sbi + (size_t)r * ldi + c];
    tile[ty + i * 8][tx] = v;
  }
  __syncthreads();
#pragma unroll
  for (int i = 0; i < 4; i++) {
    int oc = c0 + ty + i * 8, orr = r0 + tx;
    if (orr < rows) out[(size_t)bz * sbo + (size_t)oc * ldo + orr] = tile[tx][ty + i * 8];
  }
}

// ---------------- target logit: tl[r] = dot(hid[r], W[tgt[r]]) + ob[tgt] ----
__global__ __launch_bounds__(256) void k_tl(const short* __restrict__ hid,
                                            const short* __restrict__ W,
                                            const float* __restrict__ ob,
                                            const int* __restrict__ tgt,
                                            float* __restrict__ tl) {
  const int row = blockIdx.x * 4 + (threadIdx.x >> 6);
  const int lane = threadIdx.x & 63;
  const int tv = tgt[row];
  sx8 hv = *(const sx8*)(hid + (size_t)row * 512 + lane * 8);
  sx8 wv = *(const sx8*)(W + (size_t)tv * 512 + lane * 8);
  float s = 0.f;
#pragma unroll
  for (int e = 0; e < 8; e++) s += bf2f(hv[e]) * bf2f(wv[e]);
#pragma unroll
  for (int off = 32; off >= 1; off >>= 1) s += __shfl_down(s, off, 64);
  if (lane == 0) tl[row] = s + ob[tv];
}

// ---------------- merge chunk partials -> masked NLL sums -------------------
__global__ __launch_bounds__(256) void k_nll(const float* __restrict__ mp,
                                             const float* __restrict__ sp,
                                             const float* __restrict__ tl,
                                             const int* __restrict__ tgt,
                                             float* __restrict__ accum) {
  const int r = blockIdx.x * 256 + threadIdx.x;
  float M = -1e30f, Ssum = 0.f;
  for (int c = 0; c < NCHUNK; c++) {
    float m = mp[(size_t)c * 8192 + r];
    float s = sp[(size_t)c * 8192 + r];
    float nM = fmaxf(M, m);
    Ssum = Ssum * __expf(M - nM) + s * __expf(m - nM);
    M = nM;
  }
  float msk = (tgt[r] != 0) ? 1.f : 0.f;
  float nll = (M + logf(Ssum) - tl[r]) * msk;
#pragma unroll
  for (int off = 32; off >= 1; off >>= 1) {
    nll += __shfl_down(nll, off, 64);
    msk += __shfl_down(msk, off, 64);
  }
  if ((threadIdx.x & 63) == 0) {
    atomicAdd(&accum[0], nll);
    atomicAdd(&accum[1], msk);
  }
}

__global__ void k_final(const float* __restrict__ accum, float* __restrict__ out) {
  out[0] = accum[0] / accum[1];
}

// ---------------------------------------------------------------------------
extern "C" void kernel_launch(void* const* d_in, const int* in_sizes, int n_in,
                              void* d_out, int out_size, void* d_ws, size_t ws_size,
                              hipStream_t stream) {
  (void)in_sizes; (void)n_in; (void)out_size;
  const int*   numeric = (const int*)  d_in[0];
  const int*   noised  = (const int*)  d_in[1];
  const float* emb     = (const float*)d_in[2];
  const float* Wih_f   = (const float*)d_in[3];
  const float* Whh_f   = (const float*)d_in[4];
  const float* b_f     = (const float*)d_in[5];
  const float* Wih_b   = (const float*)d_in[6];
  const float* Whh_b   = (const float*)d_in[7];
  const float* b_b     = (const float*)d_in[8];
  const float* dWih    = (const float*)d_in[9];
  const float* dWhh    = (const float*)d_in[10];
  const float* d_bv    = (const float*)d_in[11];
  const float* attnW   = (const float*)d_in[12];
  const float* mlpW    = (const float*)d_in[13];
  const float* mlp_b   = (const float*)d_in[14];
  const float* outW    = (const float*)d_in[15];
  const float* out_b   = (const float*)d_in[16];
  float* out = (float*)d_out;

  char* w = (char*)d_ws;
  size_t off = 0;
  auto alloc = [&](size_t bytes) -> void* {
    void* p = w + off;
    off = (off + bytes + 255) & ~(size_t)255;
    return p;
  };
  // bf16 weights
  short* bWih_f = (short*)alloc((size_t)1024 * 512 * 2);
  short* bWih_b = (short*)alloc((size_t)1024 * 512 * 2);
  short* bWhh_f = (short*)alloc((size_t)1024 * 256 * 2);
  short* bWhh_b = (short*)alloc((size_t)1024 * 256 * 2);
  short* bWdec  = (short*)alloc((size_t)2048 * 512 * 2);
  short* bWhhd  = (short*)alloc((size_t)2048 * 512 * 2);
  short* battnW = (short*)alloc((size_t)512 * 512 * 2);
  short* bmlpW  = (short*)alloc((size_t)512 * 1024 * 2);
  short* boutW  = (short*)alloc((size_t)32768 * 512 * 2);  // zero-padded rows
  // activations (bf16)
  short* embedded  = (short*)alloc((size_t)8192 * 512 * 2);
  short* embnoised = (short*)alloc((size_t)8208 * 512 * 2);
  short* g_xwf     = (short*)alloc((size_t)8208 * 1024 * 2);
  short* g_xwb     = (short*)alloc((size_t)8208 * 1024 * 2);
  short* g_xwd     = (short*)alloc((size_t)8192 * 2048 * 2);
  short* enc       = (short*)alloc((size_t)8208 * 512 * 2);
  short* proj      = (short*)alloc((size_t)8208 * 512 * 2);
  short* scores    = (short*)alloc((size_t)16 * 513 * 512 * 2);
  short* attnT     = (short*)alloc((size_t)16 * 512 * 544 * 2);
  short* encT      = (short*)alloc((size_t)16 * 512 * 544 * 2);
  short* full      = (short*)alloc((size_t)8192 * 1024 * 2);
  short* hid       = (short*)alloc((size_t)8192 * 512 * 2);
  float* mpart     = (float*)alloc((size_t)NCHUNK * 8192 * 4);
  float* spart     = (float*)alloc((size_t)NCHUNK * 8192 * 4);
  float* tlv       = (float*)alloc((size_t)8192 * 4);
  size_t small_off = off;
  short*    zbuf  = (short*)alloc((size_t)16384 * 2);   // 32KB zeros (h0)
  unsigned* flags = (unsigned*)alloc(4096);             // 3 flag lines
  float*    accum = (float*)alloc(256);
  size_t total = off;
  if (ws_size < total) return;

  dim3 b256(256);

  // zero-init regions (ws is poisoned before every call)
  hipMemsetAsync(boutW, 0, (size_t)32768 * 512 * 2, stream);
  hipMemsetAsync(attnT, 0, (size_t)16 * 512 * 544 * 2, stream);
  hipMemsetAsync(encT, 0, (size_t)16 * 512 * 544 * 2, stream);
  hipMemsetAsync(w + small_off, 0, total - small_off, stream);

  // weight conversions
  k_f32_to_bf16<<<2048, b256, 0, stream>>>(Wih_f, bWih_f, 1024L * 512);
  k_f32_to_bf16<<<2048, b256, 0, stream>>>(Wih_b, bWih_b, 1024L * 512);
  k_f32_to_bf16<<<2048, b256, 0, stream>>>(Whh_f, bWhh_f, 1024L * 256);
  k_f32_to_bf16<<<2048, b256, 0, stream>>>(Whh_b, bWhh_b, 1024L * 256);
  k_f32_to_bf16<<<2048, b256, 0, stream>>>(dWih,  bWdec,  2048L * 512);
  k_f32_to_bf16<<<2048, b256, 0, stream>>>(dWhh,  bWhhd,  2048L * 512);
  k_f32_to_bf16<<<2048, b256, 0, stream>>>(attnW, battnW, 512L * 512);
  k_f32_to_bf16<<<2048, b256, 0, stream>>>(mlpW,  bmlpW,  512L * 1024);
  k_f32_to_bf16<<<8192, b256, 0, stream>>>(outW,  boutW,  32003L * 512);

  // embeddings
  k_embed<<<(8192 * 512 + 255) / 256, b256, 0, stream>>>(emb, numeric, embedded, 8192);
  k_embed<<<(8208 * 512 + 255) / 256, b256, 0, stream>>>(emb, noised, embnoised, 8208);

  // xW = x @ Wih^T + b  (stored bf16)
  k_gemm_bt<<<dim3(65, 8, 1), b256, 0, stream>>>(embnoised, 512, 0, bWih_f, 512, 0,
      g_xwf, nullptr, 1024, 0, b_f, 0, 8208, 1024, 512);
  k_gemm_bt<<<dim3(65, 8, 1), b256, 0, stream>>>(embnoised, 512, 0, bWih_b, 512, 0,
      g_xwb, nullptr, 1024, 0, b_b, 0, 8208, 1024, 512);
  k_gemm_bt<<<dim3(64, 16, 1), b256, 0, stream>>>(embedded, 512, 0, bWdec, 512, 0,
      g_xwd, nullptr, 2048, 0, d_bv, 0, 8192, 2048, 512);

  // recurrences (dec -> full[:, :512], enc f/b -> enc)
  k_lstm<<<12, b256, 0, stream>>>(g_xwd, bWhhd, g_xwf, bWhh_f, g_xwb, bWhh_b,
                                  full, enc, zbuf, flags);

  // proj = enc @ attn_W^T
  k_gemm_bt<<<dim3(65, 4, 1), b256, 0, stream>>>(enc, 512, 0, battnW, 512, 0,
      proj, nullptr, 512, 0, nullptr, 0, 8208, 512, 512);

  // scores[b][s][t] = sum_h proj[s,b,h] * dec[t,b,h]
  k_gemm_bt<<<dim3(5, 4, 16), b256, 0, stream>>>(proj, 8192, 512, full, 16384, 1024,
      scores, nullptr, 512, (long)513 * 512, nullptr, 0, 513, 512, 512);

  // softmax over s, in place
  k_softmax<<<dim3(2, 16), b256, 0, stream>>>(scores);

  // transposes into K-padded (544) layouts
  k_transpose<<<dim3(17, 16, 16), b256, 0, stream>>>(scores, 512, (long)513 * 512,
      attnT, 544, (long)512 * 544, 513, 512);
  k_transpose<<<dim3(17, 16, 16), b256, 0, stream>>>(enc, 8192, 512,
      encT, 544, (long)512 * 544, 513, 512);

  // ctx[t,b,h] = sum_s attn[b,s,t] enc[s,b,h]  -> full[:, 512:]
  k_gemm_bt<<<dim3(4, 4, 16), b256, 0, stream>>>(attnT, 544, (long)512 * 544,
      encT, 544, (long)512 * 544,
      full + 512, nullptr, 16384, 1024, nullptr, 0, 512, 512, 544);

  // hid = relu(full @ mlp_W^T + mlp_b)
  k_gemm_bt<<<dim3(64, 4, 1), b256, 0, stream>>>(full, 1024, 0, bmlpW, 1024, 0,
      hid, nullptr, 512, 0, mlp_b, 1, 8192, 512, 1024);

  // fused logits + chunked log-sum-exp partials
  k_gemm_lse<<<dim3(64, NCHUNK), b256, 0, stream>>>(hid, boutW, out_b, mpart, spart,
                                                    32003, 512);
  // target logits
  k_tl<<<2048, b256, 0, stream>>>(hid, boutW, out_b, numeric, tlv);
  // merge + masked mean
  k_nll<<<32, b256, 0, stream>>>(mpart, spart, tlv, numeric, accum);
  k_final<<<1, 1, 0, stream>>>(accum, out);
}